// Round 1
// baseline (439.093 us; speedup 1.0000x reference)
//
#include <hip/hip_runtime.h>

#define BATCH 524288
#define NF 128
#define WPITCH 136   // bf16 elems per LDS row: 128 + 8 pad -> 272 B pitch (16B-aligned)

typedef __attribute__((ext_vector_type(8))) short bf16x8;
typedef __attribute__((ext_vector_type(4))) float f32x4;

__device__ __forceinline__ unsigned short f2bf(float f) {
    union { float f; unsigned u; } c; c.f = f;
    unsigned r = c.u + 0x7fffu + ((c.u >> 16) & 1u);   // round-to-nearest-even
    return (unsigned short)(r >> 16);
}
__device__ __forceinline__ unsigned pk2(float lo, float hi) {
    return (unsigned)f2bf(lo) | ((unsigned)f2bf(hi) << 16);
}

// Each wave: 16 rows x 128 cols. Block = 4 waves = 64 rows. Grid = BATCH/64 = 8192.
__global__ __launch_bounds__(256, 4) void linear_kernel(
    const float* __restrict__ x, const float* __restrict__ w,
    const float* __restrict__ bias, float* __restrict__ out)
{
    __shared__ unsigned short wlds[NF * WPITCH];

    const int tid = threadIdx.x;

    // ---- Stage W (128x128 fp32, row-major [o][i]) -> LDS bf16 ----
    // 4096 float4 / 256 threads = 16 each, coalesced.
    for (int i = tid; i < NF * NF / 4; i += 256) {
        const float4 v = ((const float4*)w)[i];
        const int r = i >> 5;          // 32 float4 per row
        const int c = (i & 31) << 2;
        uint2 pv;
        pv.x = pk2(v.x, v.y);
        pv.y = pk2(v.z, v.w);
        *(uint2*)&wlds[r * WPITCH + c] = pv;   // 8B aligned: 272*r + 2c
    }
    __syncthreads();

    const int lane = tid & 63;
    const int wave = tid >> 6;
    const int m    = lane & 15;   // A row within tile / C col
    const int quad = lane >> 4;
    const int row0 = blockIdx.x * 64 + wave * 16;

    const float* xrow = x + (size_t)(row0 + m) * NF;

    f32x4 acc[8];
#pragma unroll
    for (int t = 0; t < 8; t++) acc[t] = (f32x4){0.f, 0.f, 0.f, 0.f};

#pragma unroll
    for (int kk = 0; kk < 4; kk++) {
        const int kbase = kk * 32 + quad * 8;   // A[m][k=quad*8+j], j=0..7

        // A fragment: 8 contiguous fp32 from this lane's x row -> bf16x8
        const float4 a0 = *(const float4*)(xrow + kbase);
        const float4 a1 = *(const float4*)(xrow + kbase + 4);
        union { bf16x8 v; unsigned u[4]; } af;
        af.u[0] = pk2(a0.x, a0.y);
        af.u[1] = pk2(a0.z, a0.w);
        af.u[2] = pk2(a1.x, a1.y);
        af.u[3] = pk2(a1.z, a1.w);

#pragma unroll
        for (int t = 0; t < 8; t++) {
            // B fragment: B[n=lane&15][k=quad*8+j] = W[o=t*16+m][i=kbase..kbase+7]
            const bf16x8 bfrag = *(const bf16x8*)&wlds[(t * 16 + m) * WPITCH + kbase];
            acc[t] = __builtin_amdgcn_mfma_f32_16x16x32_bf16(af.v, bfrag, acc[t], 0, 0, 0);
        }
    }

    // ---- Epilogue: C/D layout col = lane&15, row = quad*4 + reg ----
    float* obase = out + (size_t)(row0 + quad * 4) * NF + m;
#pragma unroll
    for (int t = 0; t < 8; t++) {
        const float bv = bias[t * 16 + m];
#pragma unroll
        for (int r = 0; r < 4; r++) {
            obase[(size_t)r * NF + t * 16] = acc[t][r] + bv;
        }
    }
}

extern "C" void kernel_launch(void* const* d_in, const int* in_sizes, int n_in,
                              void* d_out, int out_size, void* d_ws, size_t ws_size,
                              hipStream_t stream) {
    const float* x    = (const float*)d_in[0];   // enc_x  (524288, 128)
    const float* w    = (const float*)d_in[1];   // weight (128, 128)
    const float* bias = (const float*)d_in[2];   // bias   (128,)
    float* out = (float*)d_out;                  // (524288, 128)

    linear_kernel<<<BATCH / 64, 256, 0, stream>>>(x, w, bias, out);
}